// Round 1
// baseline (774.061 us; speedup 1.0000x reference)
//
#include <hip/hip_runtime.h>
#include <math.h>

#define TPB 128
#define NBLK 6

// deriv normalization: 1/(MIN_D + ln 2)
#define DNORM (1.0f / (0.001f + 0.69314718055994530942f))

__device__ __forceinline__ float leaky(float a) { return a >= 0.f ? a : 0.01f * a; }

__global__ __launch_bounds__(TPB, 2) void flow_kernel(
    const float* __restrict__ X, const float* __restrict__ C4,
    const float* __restrict__ W1, const float* __restrict__ B1,
    const float* __restrict__ W2, const float* __restrict__ B2,
    const float* __restrict__ W3, const float* __restrict__ B3,
    float* __restrict__ JAC, int n)
{
    __shared__ float h2s[64][TPB];   // k-major: h2s[k][tid], per-lane column -> no conflicts, no barriers
    const int tid = threadIdx.x;
    const int gid = blockIdx.x * TPB + tid;
    if (gid >= n) return;

    const float4 xa = reinterpret_cast<const float4*>(X)[gid * 2 + 0];
    const float4 xb = reinterpret_cast<const float4*>(X)[gid * 2 + 1];
    const float4 cv = reinterpret_cast<const float4*>(C4)[gid];
    float xr0 = xa.x, xr1 = xa.y, xr2 = xa.z, xr3 = xa.w;
    float xr4 = xb.x, xr5 = xb.y, xr6 = xb.z, xr7 = xb.w;

    float jac = 0.f;

    for (int blk = 0; blk < NBLK; ++blk) {
        const int p    = blk >> 1;
        const int flip = blk & 1;
        const int cbit = flip ^ 1;
        const int lm   = (1 << p) - 1;

        int cd[4], td[4];
        #pragma unroll
        for (int j = 0; j < 4; ++j) {
            cd[j] = ((j >> p) << (p + 1)) | (cbit << p) | (j & lm);
            td[j] = ((j >> p) << (p + 1)) | ((cbit ^ 1) << p) | (j & lm);
        }

        // gather conditioning inputs: x[cond dims] ++ c
        float xc[8];
        #pragma unroll
        for (int j = 0; j < 4; ++j) {
            const int i = cd[j];
            float v = xr0;
            v = (i == 1) ? xr1 : v; v = (i == 2) ? xr2 : v; v = (i == 3) ? xr3 : v;
            v = (i == 4) ? xr4 : v; v = (i == 5) ? xr5 : v; v = (i == 6) ? xr6 : v;
            v = (i == 7) ? xr7 : v;
            xc[j] = v;
        }
        xc[4] = cv.x; xc[5] = cv.y; xc[6] = cv.z; xc[7] = cv.w;

        const float* w1 = W1 + blk * 8 * 64;
        const float* w2 = W2 + blk * 64 * 64;
        const float* w3 = W3 + blk * 64 * 124;
        const float* b1 = B1 + blk * 64;
        const float* b2 = B2 + blk * 64;
        const float* b3 = B3 + blk * 124;

        // ---- layer 1: 8 -> 64, fully unrolled, h1 in VGPRs (k-outer: contiguous uniform loads)
        float h1[64];
        #pragma unroll
        for (int u = 0; u < 64; ++u) h1[u] = b1[u];
        #pragma unroll
        for (int k = 0; k < 8; ++k) {
            const float xk = xc[k];
            #pragma unroll
            for (int u = 0; u < 64; ++u) h1[u] = fmaf(xk, w1[k * 64 + u], h1[u]);
        }
        #pragma unroll
        for (int u = 0; u < 64; ++u) h1[u] = leaky(h1[u]);

        // ---- layer 2: 64 -> 64, runtime u-chunks; h1 from regs (static k), h2 -> LDS
        #pragma unroll 1
        for (int uo = 0; uo < 8; ++uo) {
            float acc[8];
            #pragma unroll
            for (int j = 0; j < 8; ++j) acc[j] = b2[uo * 8 + j];
            #pragma unroll
            for (int k = 0; k < 64; ++k) {
                const float hk = h1[k];
                #pragma unroll
                for (int j = 0; j < 8; ++j)
                    acc[j] = fmaf(hk, w2[k * 64 + uo * 8 + j], acc[j]);
            }
            #pragma unroll
            for (int j = 0; j < 8; ++j) h2s[uo * 8 + j][tid] = leaky(acc[j]);
        }

        // trafo-dim inputs (pre-transform values) + inside flag
        float xt[4];
        #pragma unroll
        for (int j = 0; j < 4; ++j) {
            const int i = td[j];
            float v = xr0;
            v = (i == 1) ? xr1 : v; v = (i == 2) ? xr2 : v; v = (i == 3) ? xr3 : v;
            v = (i == 4) ? xr4 : v; v = (i == 5) ? xr5 : v; v = (i == 6) ? xr6 : v;
            v = (i == 7) ? xr7 : v;
            xt[j] = v;
        }
        const bool inside =
            (xt[0] >= 0.f) && (xt[0] <= 1.f) && (xt[1] >= 0.f) && (xt[1] <= 1.f) &&
            (xt[2] >= 0.f) && (xt[2] <= 1.f) && (xt[3] >= 0.f) && (xt[3] <= 1.f);

        // ---- per trafo dim: layer-3 slice (64 -> 31) + RQ spline
        #pragma unroll
        for (int t = 0; t < 4; ++t) {
            float o[31];
            #pragma unroll
            for (int j = 0; j < 31; ++j) o[j] = b3[t * 31 + j];
            #pragma unroll 4
            for (int k = 0; k < 64; ++k) {
                const float hk = h2s[k][tid];
                #pragma unroll
                for (int j = 0; j < 31; ++j)
                    o[j] = fmaf(hk, w3[k * 124 + t * 31 + j], o[j]);
            }

            // widths: softmax(o[0..9]) -> cumsum with forced endpoints, then diff
            float mw = o[0];
            #pragma unroll
            for (int k = 1; k < 10; ++k) mw = fmaxf(mw, o[k]);
            float ew[10], sw = 0.f;
            #pragma unroll
            for (int k = 0; k < 10; ++k) { ew[k] = __expf(o[k] - mw); sw += ew[k]; }
            const float fw = 0.99f / sw;
            float Cw[11];
            Cw[0] = 0.f;
            #pragma unroll
            for (int k = 1; k <= 10; ++k) Cw[k] = Cw[k - 1] + (0.001f + ew[k - 1] * fw);
            Cw[10] = 1.0f;
            float Wd[10];
            #pragma unroll
            for (int k = 0; k < 10; ++k) Wd[k] = Cw[k + 1] - Cw[k];

            // heights: softmax(o[10..19])
            float mh = o[10];
            #pragma unroll
            for (int k = 1; k < 10; ++k) mh = fmaxf(mh, o[10 + k]);
            float eh[10], sh = 0.f;
            #pragma unroll
            for (int k = 0; k < 10; ++k) { eh[k] = __expf(o[10 + k] - mh); sh += eh[k]; }
            const float fh = 0.99f / sh;
            float Ch[11];
            Ch[0] = 0.f;
            #pragma unroll
            for (int k = 1; k <= 10; ++k) Ch[k] = Ch[k - 1] + (0.001f + eh[k - 1] * fh);
            Ch[10] = 1.0f;
            float Hh[10];
            #pragma unroll
            for (int k = 0; k < 10; ++k) Hh[k] = Ch[k + 1] - Ch[k];

            // derivatives: (MIN_D + softplus(o[20..30])) / (MIN_D + ln2)
            float dv[11];
            #pragma unroll
            for (int k = 0; k < 11; ++k) {
                const float u = o[20 + k];
                const float sp = (u > 15.f) ? u : __logf(1.f + __expf(u));
                dv[k] = (0.001f + sp) * DNORM;
            }

            // bin search + gathers via compare-select scan (inner knots Cw[1..9])
            const float xin = fminf(fmaxf(xt[t], 0.f), 1.f);
            float in_cw = 0.f, in_bw = Wd[0], in_ch = 0.f, in_h = Hh[0];
            float in_d = dv[0], in_dp1 = dv[1];
            #pragma unroll
            for (int k = 1; k < 10; ++k) {
                const bool ge = (xin >= Cw[k]);
                in_cw  = ge ? Cw[k]     : in_cw;
                in_bw  = ge ? Wd[k]     : in_bw;
                in_ch  = ge ? Ch[k]     : in_ch;
                in_h   = ge ? Hh[k]     : in_h;
                in_d   = ge ? dv[k]     : in_d;
                in_dp1 = ge ? dv[k + 1] : in_dp1;
            }

            const float th   = (xin - in_cw) / in_bw;
            const float tomt = th * (1.f - th);
            const float dl   = in_h / in_bw;
            const float nume = in_h * (dl * th * th + in_d * tomt);
            const float deno = dl + (in_d + in_dp1 - 2.f * dl) * tomt;
            const float xout = in_ch + nume / deno;
            const float omt  = 1.f - th;
            const float dnum = dl * dl * (in_dp1 * th * th + 2.f * dl * tomt + in_d * omt * omt);
            const float lad  = __logf(dnum) - 2.f * __logf(deno);

            const float xnew = inside ? xout : xt[t];
            jac += inside ? lad : 0.f;

            const int ti = td[t];
            xr0 = (ti == 0) ? xnew : xr0; xr1 = (ti == 1) ? xnew : xr1;
            xr2 = (ti == 2) ? xnew : xr2; xr3 = (ti == 3) ? xnew : xr3;
            xr4 = (ti == 4) ? xnew : xr4; xr5 = (ti == 5) ? xnew : xr5;
            xr6 = (ti == 6) ? xnew : xr6; xr7 = (ti == 7) ? xnew : xr7;
        }
    }
    JAC[gid] = jac;
}

extern "C" void kernel_launch(void* const* d_in, const int* in_sizes, int n_in,
                              void* d_out, int out_size, void* d_ws, size_t ws_size,
                              hipStream_t stream) {
    (void)n_in; (void)d_ws; (void)ws_size;
    const float* X  = (const float*)d_in[0];
    const float* C4 = (const float*)d_in[1];
    const float* W1 = (const float*)d_in[2];
    const float* B1 = (const float*)d_in[3];
    const float* W2 = (const float*)d_in[4];
    const float* B2 = (const float*)d_in[5];
    const float* W3 = (const float*)d_in[6];
    const float* B3 = (const float*)d_in[7];
    float* out = (float*)d_out;

    const int n = in_sizes[0] / 8;                 // 262144
    dim3 grid((n + TPB - 1) / TPB), block(TPB);
    hipLaunchKernelGGL(flow_kernel, grid, block, 0, stream,
                       X, C4, W1, B1, W2, B2, W3, B3, out, n);
}